// Round 4
// baseline (30505.746 us; speedup 1.0000x reference)
//
#include <hip/hip_runtime.h>
#include <hip/hip_bf16.h>
#include <math.h>

#define NB 32
#define NKS 2048
#define NKG 512
#define NH 512
#define NH3 1536
#define NV 32000
#define NSTEPS 64

typedef unsigned long long u64;
typedef unsigned int u32;
typedef unsigned short u16;
typedef __attribute__((ext_vector_type(8))) short short8;
typedef __attribute__((ext_vector_type(4))) float f32x4;

__device__ __forceinline__ float bfu(u32 u){ return __uint_as_float(u << 16); }
__device__ __forceinline__ u16 f2bf(float f){
  u32 b = __float_as_uint(f);
  return (u16)((b + 0x7FFFu + ((b>>16)&1u)) >> 16);
}

// monotone pack: larger float -> larger u64; equal float -> smaller index wins
__device__ __forceinline__ u64 packv(float v, int idx){
  u32 u = __float_as_uint(v);
  u = (u & 0x80000000u) ? ~u : (u | 0x80000000u);
  return (((u64)u) << 32) | (u32)(~(u32)idx);
}
__device__ __forceinline__ float unpackv(u64 p){
  u32 hi = (u32)(p >> 32);
  u32 u = (hi & 0x80000000u) ? (hi ^ 0x80000000u) : ~hi;
  return __uint_as_float(u);
}

// ---------------- one-time: fp32 -> bf16 (RNE) copies of both encoders -------
__global__ void k_cast(const float* __restrict__ sent, const float* __restrict__ graph,
                       u16* __restrict__ dsts, u16* __restrict__ dstg){
  const long NSg = (long)NB*NKS*NH/8;
  const long NGg = (long)NB*NKG*NH/8;
  long stride = (long)gridDim.x*blockDim.x;
  for (long g = (long)blockIdx.x*blockDim.x + threadIdx.x; g < NSg+NGg; g += stride){
    const float* src; u16* dst; long gg;
    if (g < NSg){ src = sent; dst = dsts; gg = g; } else { src = graph; dst = dstg; gg = g - NSg; }
    const float4* s4 = (const float4*)src + gg*2;
    float4 a = s4[0], b = s4[1];
    float vals[8] = {a.x,a.y,a.z,a.w,b.x,b.y,b.z,b.w};
    u16 o[8];
    #pragma unroll
    for (int i=0;i<8;i++) o[i] = f2bf(vals[i]);
    uint4 out;
    out.x = (u32)o[0] | ((u32)o[1]<<16);
    out.y = (u32)o[2] | ((u32)o[3]<<16);
    out.z = (u32)o[4] | ((u32)o[5]<<16);
    out.w = (u32)o[6] | ((u32)o[7]<<16);
    *((uint4*)dst + gg) = out;
  }
}

// ---- one-time: pack W_out into bf16 MFMA B-fragment order ----
__global__ void k_packw(const float* __restrict__ W, u16* __restrict__ wp){
  long t = (long)blockIdx.x*256 + threadIdx.x;   // 6,144,000 total
  int lane = (int)(t & 63);
  long g = t >> 6;
  int kc = (int)(g % 48);
  int v16 = (int)(g / 48);
  int v = v16*16 + (lane&15);
  int k0 = kc*32 + (lane>>4)*8;
  const float4* src = (const float4*)(W + (size_t)v*NH3 + k0);
  float4 a = src[0], b = src[1];
  float vals[8] = {a.x,a.y,a.z,a.w,b.x,b.y,b.z,b.w};
  u16 o[8];
  #pragma unroll
  for (int i=0;i<8;i++) o[i] = f2bf(vals[i]);
  uint4 out;
  out.x = (u32)o[0] | ((u32)o[1]<<16);
  out.y = (u32)o[2] | ((u32)o[3]<<16);
  out.z = (u32)o[4] | ((u32)o[5]<<16);
  out.w = (u32)o[6] | ((u32)o[7]<<16);
  ((uint4*)wp)[t] = out;
}

__global__ void k_init(const float* __restrict__ enc, double* __restrict__ hd){
  int i = blockIdx.x*256 + threadIdx.x;   // grid 64x256 == NB*NH
  hd[i] = (double)enc[i];
}

// -------- per step (fp64): q = Wa@h, gx = Wih@emb[inp]+b, gh = Whh@h+b -------
// blockIdx = ot*4 + bq ; ot in 0..55 (8 q-tiles, 24 gx, 24 gh), bq = 8-batch group
__global__ __launch_bounds__(256) void k_gates(
    const double* __restrict__ hd, const float* __restrict__ Wa,
    const float* __restrict__ Wih, const float* __restrict__ Whh,
    const float* __restrict__ bih, const float* __restrict__ bhh,
    const float* __restrict__ emb, const u64* __restrict__ packed_ex,
    double* __restrict__ qd, float* __restrict__ qf,
    double* __restrict__ gxd, double* __restrict__ ghd, int step)
{
  __shared__ double xs[8*512];           // 32 KB
  int blk = blockIdx.x, tid = threadIdx.x;
  int ot = blk >> 2, bq = blk & 3;
  int b0 = bq*8;
  int typ = (ot < 8) ? 0 : (ot < 32 ? 1 : 2);
  const u64* prev = packed_ex + ((step+1)&1)*NB;
  if (typ != 1){
    for (int i=tid; i<8*512; i+=256) xs[i] = hd[(size_t)b0*NH + i];
  } else {
    for (int i=tid; i<8*512; i+=256){
      int bb = i>>9;
      int inp = (step==0) ? 1 : (int)(~(u32)prev[b0+bb]);
      xs[i] = (double)emb[(size_t)inp*NH + (i&511)];
    }
  }
  __syncthreads();
  int lane = tid&63, wv = tid>>6;
  const float* wrow; double bias; int dcol;
  if (typ==0){ dcol = ot*64 + lane; wrow = Wa + (size_t)dcol*NH; bias = 0.0; }
  else if (typ==1){ dcol = (ot-8)*64 + lane; wrow = Wih + (size_t)dcol*NH; bias = (double)bih[dcol]; }
  else { dcol = (ot-32)*64 + lane; wrow = Whh + (size_t)dcol*NH; bias = (double)bhh[dcol]; }
  const float4* w4 = (const float4*)wrow;
  int s0 = wv*2, s1 = s0+1;
  double acc0 = 0.0, acc1 = 0.0;
  for (int k4=0;k4<128;k4++){
    float4 w = w4[k4];
    int k = k4*4;
    acc0 += (double)w.x*xs[s0*512+k]   + (double)w.y*xs[s0*512+k+1]
          + (double)w.z*xs[s0*512+k+2] + (double)w.w*xs[s0*512+k+3];
    acc1 += (double)w.x*xs[s1*512+k]   + (double)w.y*xs[s1*512+k+1]
          + (double)w.z*xs[s1*512+k+2] + (double)w.w*xs[s1*512+k+3];
  }
  acc0 += bias; acc1 += bias;
  int ba = b0+s0, bb2 = b0+s1;
  if (typ==0){
    qd[(size_t)ba*NH+dcol] = acc0; qf[(size_t)ba*NH+dcol] = (float)acc0;
    qd[(size_t)bb2*NH+dcol] = acc1; qf[(size_t)bb2*NH+dcol] = (float)acc1;
  } else if (typ==1){
    gxd[(size_t)ba*NH3+dcol] = acc0; gxd[(size_t)bb2*NH3+dcol] = acc1;
  } else {
    ghd[(size_t)ba*NH3+dcol] = acc0; ghd[(size_t)bb2*NH3+dcol] = acc1;
  }
}

// ------------- per step: approximate scores, row-per-wave coalesced ----------
template<int BF>
__global__ __launch_bounds__(256) void k_scores2(
   const u16* __restrict__ sh, const u16* __restrict__ g16,
   const float* __restrict__ sf, const float* __restrict__ gf,
   const float* __restrict__ qf,
   float* __restrict__ ss, float* __restrict__ sg,
   float* __restrict__ tms, float* __restrict__ tmg)
{
  int blk = blockIdx.x, tid = threadIdx.x;
  int b, tile, K, nt; const u16* srch; const float* srcf; float* sc; float* tm;
  if (blk < 256){ b = blk>>3; tile = blk&7; K = NKS; srch = sh;  srcf = sf; sc = ss; tm = tms; nt=8; }
  else { int bb = blk-256; b = bb>>1; tile = bb&1; K = NKG; srch = g16; srcf = gf; sc = sg; tm = tmg; nt=2; }
  int wv = tid>>6, lane = tid&63;
  float qv[8];
  { const float4* q4 = (const float4*)(qf + b*NH) + lane*2;
    float4 qa = q4[0], qb = q4[1];
    qv[0]=qa.x; qv[1]=qa.y; qv[2]=qa.z; qv[3]=qa.w;
    qv[4]=qb.x; qv[5]=qb.y; qv[6]=qb.z; qv[7]=qb.w; }
  int kbase = tile*256 + wv*64;
  float my = 0.f, wmax = -1e30f;
  #pragma unroll 2
  for (int r=0;r<64;r++){
    int key = kbase + r;
    float acc;
    if (BF){
      uint4 u = *((const uint4*)(srch + ((size_t)b*K + key)*NH) + lane);
      acc = bfu(u.x&0xffffu)*qv[0]+bfu(u.x>>16)*qv[1]+bfu(u.y&0xffffu)*qv[2]+bfu(u.y>>16)*qv[3]
           +bfu(u.z&0xffffu)*qv[4]+bfu(u.z>>16)*qv[5]+bfu(u.w&0xffffu)*qv[6]+bfu(u.w>>16)*qv[7];
    } else {
      const float4* rw = (const float4*)(srcf + ((size_t)b*K + key)*NH) + lane*2;
      float4 p0 = rw[0], p1 = rw[1];
      acc = p0.x*qv[0]+p0.y*qv[1]+p0.z*qv[2]+p0.w*qv[3]
           +p1.x*qv[4]+p1.y*qv[5]+p1.z*qv[6]+p1.w*qv[7];
    }
    #pragma unroll
    for (int off=32;off>=1;off>>=1) acc += __shfl_xor(acc, off);
    wmax = fmaxf(wmax, acc);
    if (r == lane) my = acc;
  }
  sc[(size_t)b*K + kbase + lane] = my;
  __shared__ float red[4];
  if (lane==0) red[wv] = wmax;
  __syncthreads();
  if (tid==0) tm[b*nt + tile] = fmaxf(fmaxf(red[0],red[1]), fmaxf(red[2],red[3]));
}

// -- per step: select keys > max-30, exact fp64 scores + weighted values ------
__global__ __launch_bounds__(256) void k_ct(
  const float* __restrict__ sf, const float* __restrict__ gf,
  const double* __restrict__ qd,
  const float* __restrict__ ss, const float* __restrict__ sg,
  const float* __restrict__ tms, const float* __restrict__ tmg,
  double* __restrict__ pcs, double* __restrict__ pcg,
  double* __restrict__ pds, double* __restrict__ pdg)
{
  int blk = blockIdx.x, tid = threadIdx.x;
  int b, tile, K, nt; const float* src; const float* sc; const float* tm;
  double* pct; double* pden;
  if (blk < 256){ b=blk>>3; tile=blk&7; K=NKS; nt=8; src=sf; sc=ss; tm=tms; pct=pcs; pden=pds; }
  else { int bb=blk-256; b=bb>>1; tile=bb&1; K=NKG; nt=2; src=gf; sc=sg; tm=tmg; pct=pcg; pden=pdg; }
  __shared__ double qs[NH];   // 4 KB
  for (int i=tid;i<NH;i+=256) qs[i] = qd[b*NH+i];
  float m = -1e30f;
  for (int i=0;i<nt;i++) m = fmaxf(m, tm[b*nt+i]);
  __syncthreads();
  int key = tile*256 + tid;
  float s = sc[(size_t)b*K + key];
  bool selp = (s > m - 30.0f);
  u64 mb = __ballot(selp);
  int lane = tid&63, wv = tid>>6;
  __shared__ int wcnt[4]; __shared__ int wbase[5];
  if (lane==0) wcnt[wv] = __popcll(mb);
  __syncthreads();
  if (tid==0){ int r=0; for (int w=0;w<4;w++){ wbase[w]=r; r+=wcnt[w]; } wbase[4]=r; }
  __syncthreads();
  int n = wbase[4];
  __shared__ int sel[256]; __shared__ double wexp[256];
  if (selp){
    int pos = wbase[wv] + __popcll(mb & ((1ULL<<lane)-1ULL));  // deterministic compaction
    sel[pos] = key;
  }
  __syncthreads();
  // exact fp64 scores for survivors: one wave per key
  double md = (double)m;
  for (int i=wv; i<n; i+=4){
    const float* vr = src + ((size_t)b*K + sel[i])*NH;
    const float4* vr4 = (const float4*)vr + lane*2;
    float4 p0 = vr4[0], p1 = vr4[1];
    int hb = lane*8;
    double a = (double)p0.x*qs[hb+0]+(double)p0.y*qs[hb+1]+(double)p0.z*qs[hb+2]+(double)p0.w*qs[hb+3]
             + (double)p1.x*qs[hb+4]+(double)p1.y*qs[hb+5]+(double)p1.z*qs[hb+6]+(double)p1.w*qs[hb+7];
    #pragma unroll
    for (int off=32; off>=1; off>>=1) a += __shfl_xor(a, off);
    if (lane==0) wexp[i] = exp(a - md);   // common reference m per (b,encoder): cancels in ratio
  }
  __syncthreads();
  double den = 0.0;
  for (int i=0;i<n;i++) den += wexp[i];
  double c0=0.0, c1=0.0; int h0 = tid*2;
  for (int i=0;i<n;i++){
    double w = wexp[i];
    const float2 vv = *(const float2*)(src + ((size_t)b*K + sel[i])*NH + h0);
    c0 += w*(double)vv.x; c1 += w*(double)vv.y;
  }
  double* pout = pct + ((size_t)(b*nt + tile))*NH;
  pout[h0] = c0; pout[h0+1] = c1;
  if (tid==0) pden[b*nt+tile] = den;
}

// -- per step (fp64): combine partials, GRU, x = [h', ct_g, ct_s]; bf16 frags -
__global__ __launch_bounds__(256) void k_comb(
  const double* __restrict__ pcs, const double* __restrict__ pcg,
  const double* __restrict__ pds, const double* __restrict__ pdg,
  const double* __restrict__ gxd, const double* __restrict__ ghd,
  double* __restrict__ hd, double* __restrict__ xd, u16* __restrict__ apack,
  u64* __restrict__ pbf_cur, u64* __restrict__ pex_cur)
{
  int b = blockIdx.x, tid = threadIdx.x;
  if (tid==0){ pbf_cur[b] = 0ULL; pex_cur[b] = 0ULL; }
  double dens = 0.0, deng = 0.0;
  for (int i=0;i<8;i++) dens += pds[b*8+i];
  for (int i=0;i<2;i++) deng += pdg[b*2+i];
  int mt = b>>4, row = b&15;
  for (int i=tid; i<NH; i+=256){
    double cs = 0.0; for (int t=0;t<8;t++) cs += pcs[((size_t)(b*8+t))*NH + i];
    double cg = 0.0; for (int t=0;t<2;t++) cg += pcg[((size_t)(b*2+t))*NH + i];
    cs /= dens; cg /= deng;
    double xr = gxd[(size_t)b*NH3 + i],        hr = ghd[(size_t)b*NH3 + i];
    double xz = gxd[(size_t)b*NH3 + NH + i],   hz = ghd[(size_t)b*NH3 + NH + i];
    double xn = gxd[(size_t)b*NH3 + 2*NH + i], hn = ghd[(size_t)b*NH3 + 2*NH + i];
    double r = 1.0/(1.0+exp(-(xr+hr)));
    double z = 1.0/(1.0+exp(-(xz+hz)));
    double nn = tanh(xn + r*hn);
    double hold = hd[(size_t)b*NH + i];
    double hnew = (1.0 - z)*nn + z*hold;
    hd[(size_t)b*NH + i] = hnew;
    double vals[3] = {hnew, cg, cs};
    #pragma unroll
    for (int c=0;c<3;c++){
      int col = c*NH + i;
      xd[(size_t)b*NH3 + col] = vals[c];
      int kc = col>>5, kg = (col&31)>>3, j = col&7;
      int lane = row + 16*kg;
      size_t base = ((size_t)(mt*48+kc)*64 + lane)*8 + j;
      float xf = (float)vals[c];
      u16 hi = f2bf(xf);
      float rem = (float)(vals[c] - (double)bfu((u32)hi));
      apack[base] = hi;
      apack[base + (size_t)2*48*64*8] = f2bf(rem);   // lo block after hi block
    }
  }
}

// --------- per step: logits via split-bf16 MFMA from packed fragments --------
__global__ __launch_bounds__(256) void k_logv(
  const u16* __restrict__ apack, const u16* __restrict__ wpack,
  const float* __restrict__ bout, float* __restrict__ dst,
  u64* __restrict__ pbf_cur)
{
  int tid = threadIdx.x;
  int wv = tid>>6, lane = tid&63;
  int v16 = blockIdx.x*4 + wv;                    // 500 blocks -> 2000 tiles
  const short8* bp = (const short8*)wpack + (size_t)v16*48*64 + lane;
  const short8* ap = (const short8*)apack + lane;
  f32x4 acc0 = {0.f,0.f,0.f,0.f}, acc1 = {0.f,0.f,0.f,0.f};
  #pragma unroll 4
  for (int kc=0; kc<48; kc++){
    short8 bf = bp[(size_t)kc*64];
    short8 a0h = ap[(size_t)kc*64];
    short8 a1h = ap[(size_t)(48+kc)*64];
    short8 a0l = ap[(size_t)(96+kc)*64];
    short8 a1l = ap[(size_t)(144+kc)*64];
    acc0 = __builtin_amdgcn_mfma_f32_16x16x32_bf16(a0h, bf, acc0, 0, 0, 0);
    acc0 = __builtin_amdgcn_mfma_f32_16x16x32_bf16(a0l, bf, acc0, 0, 0, 0);
    acc1 = __builtin_amdgcn_mfma_f32_16x16x32_bf16(a1h, bf, acc1, 0, 0, 0);
    acc1 = __builtin_amdgcn_mfma_f32_16x16x32_bf16(a1l, bf, acc1, 0, 0, 0);
  }
  __shared__ u64 smax[NB];
  if (tid < NB) smax[tid] = 0ULL;
  __syncthreads();
  int col = v16*16 + (lane&15);
  float bias = bout[col];
  int r0 = (lane>>4)*4;
  #pragma unroll
  for (int r=0;r<4;r++){
    int b0 = r0 + r;
    float v0 = acc0[r] + bias;
    dst[(size_t)b0*NV + col] = v0;
    atomicMax(&smax[b0], packv(v0, col));
    int b1 = 16 + b0;
    float v1 = acc1[r] + bias;
    dst[(size_t)b1*NV + col] = v1;
    atomicMax(&smax[b1], packv(v1, col));
  }
  __syncthreads();
  if (tid < NB) atomicMax(&pbf_cur[tid], smax[tid]);
}

// ---- per step: fp64 argmax among near-max candidates (robust, no cap-drop) --
__global__ __launch_bounds__(256) void k_refine(
  float* __restrict__ logits, const double* __restrict__ xd,
  const float* __restrict__ Wout, const float* __restrict__ bout,
  const u64* __restrict__ pbf_cur, u64* __restrict__ pex_cur)
{
  int b = blockIdx.x, tid = threadIdx.x;
  __shared__ double xs[NH3];          // 12 KB
  for (int i=tid;i<NH3;i+=256) xs[i] = xd[(size_t)b*NH3 + i];
  float maxv = unpackv(pbf_cur[b]);
  __shared__ int cnt;
  __shared__ int cand[2048];          // 8 KB
  __shared__ double cval[2048];       // 16 KB
  const float4* lg = (const float4*)(logits + (size_t)b*NV);
  float margin = 1.0f;
  for (int attempt=0; attempt<2; attempt++){
    if (tid==0) cnt = 0;
    __syncthreads();
    float thr = maxv - margin;
    for (int i=tid; i<NV/4; i+=256){
      float4 v = lg[i];
      if (v.x>thr){ int p=atomicAdd(&cnt,1); if(p<2048) cand[p]=i*4+0; }
      if (v.y>thr){ int p=atomicAdd(&cnt,1); if(p<2048) cand[p]=i*4+1; }
      if (v.z>thr){ int p=atomicAdd(&cnt,1); if(p<2048) cand[p]=i*4+2; }
      if (v.w>thr){ int p=atomicAdd(&cnt,1); if(p<2048) cand[p]=i*4+3; }
    }
    __syncthreads();
    if (cnt <= 2048) break;
    margin = 0.125f;                  // bulk err << 0.125, true argmax still included
    __syncthreads();
  }
  int n = min(cnt, 2048);
  int wv = tid>>6, lane = tid&63;
  for (int c=wv; c<n; c+=4){
    int v = cand[c];
    const float4* wr = (const float4*)(Wout + (size_t)v*NH3);
    double a = 0.0;
    #pragma unroll
    for (int i=0;i<6;i++){
      int e = lane + 64*i;
      float4 w4 = wr[e];
      a += (double)w4.x*xs[e*4+0] + (double)w4.y*xs[e*4+1]
         + (double)w4.z*xs[e*4+2] + (double)w4.w*xs[e*4+3];
    }
    #pragma unroll
    for (int off=32; off>=1; off>>=1) a += __shfl_xor(a, off);
    if (lane==0){
      double av = a + (double)bout[v];
      cval[c] = av;
      logits[(size_t)b*NV + v] = (float)av;
    }
  }
  __syncthreads();
  if (tid==0){
    double bv = -1e300; int bi = 0x7fffffff;
    for (int c=0;c<n;c++){
      if (cval[c] > bv || (cval[c] == bv && cand[c] < bi)){ bv = cval[c]; bi = cand[c]; }
    }
    pex_cur[b] = packv((float)bv, bi);
  }
}

// -------- fp32 fallback bulk logits (used only if ws can't hold packed W) ----
__global__ __launch_bounds__(256) void k_logits(
  const double* __restrict__ xd, const float* __restrict__ Wout,
  const float* __restrict__ bout, float* __restrict__ dst,
  u64* __restrict__ pbf_cur)
{
  __shared__ float4 xs4[NB*128];
  int tid = threadIdx.x;
  int bg = tid>>6, lane = tid&63;
  int vbase = blockIdx.x*128;
  int v0 = vbase + lane, v1 = vbase + 64 + lane;
  float acc0[8] = {0.f,0.f,0.f,0.f,0.f,0.f,0.f,0.f};
  float acc1[8] = {0.f,0.f,0.f,0.f,0.f,0.f,0.f,0.f};
  for (int c=0;c<3;c++){
    int kb = c*NH;
    for (int i=tid;i<NB*128;i+=256){
      int b=i>>7, kk=i&127;
      float4 t;
      t.x = (float)xd[(size_t)b*NH3 + kb + kk*4+0];
      t.y = (float)xd[(size_t)b*NH3 + kb + kk*4+1];
      t.z = (float)xd[(size_t)b*NH3 + kb + kk*4+2];
      t.w = (float)xd[(size_t)b*NH3 + kb + kk*4+3];
      xs4[i] = t;
    }
    __syncthreads();
    const float4* w0 = (const float4*)(Wout + (size_t)v0*NH3 + kb);
    const float4* w1 = (const float4*)(Wout + (size_t)v1*NH3 + kb);
    for (int k4=0;k4<128;k4++){
      float4 a = w0[k4], bb = w1[k4];
      #pragma unroll
      for (int j=0;j<8;j++){
        float4 xv = xs4[(bg*8+j)*128 + k4];
        acc0[j] += a.x*xv.x;  acc0[j] += a.y*xv.y;  acc0[j] += a.z*xv.z;  acc0[j] += a.w*xv.w;
        acc1[j] += bb.x*xv.x; acc1[j] += bb.y*xv.y; acc1[j] += bb.z*xv.z; acc1[j] += bb.w*xv.w;
      }
    }
    __syncthreads();
  }
  u64* smax = (u64*)xs4;
  if (tid<NB) smax[tid] = 0ULL;
  __syncthreads();
  float b0 = bout[v0], b1 = bout[v1];
  #pragma unroll
  for (int j=0;j<8;j++){
    int b = bg*8+j;
    float r0 = acc0[j]+b0, r1 = acc1[j]+b1;
    dst[(size_t)b*NV + v0] = r0;
    dst[(size_t)b*NV + v1] = r1;
    u64 p0 = packv(r0, v0), p1 = packv(r1, v1);
    atomicMax(&smax[b], p0>p1?p0:p1);
  }
  __syncthreads();
  if (tid<NB) atomicMax(&pbf_cur[tid], smax[tid]);
}

extern "C" void kernel_launch(void* const* d_in, const int* in_sizes, int n_in,
                              void* d_out, int out_size, void* d_ws, size_t ws_size,
                              hipStream_t stream) {
  const float* sent  = (const float*)d_in[0];
  const float* graph = (const float*)d_in[1];
  const float* enc   = (const float*)d_in[2];
  const float* Wa    = (const float*)d_in[3];
  const float* emb   = (const float*)d_in[4];
  const float* Wih   = (const float*)d_in[5];
  const float* Whh   = (const float*)d_in[6];
  const float* bih   = (const float*)d_in[7];
  const float* bhh   = (const float*)d_in[8];
  const float* Wout  = (const float*)d_in[9];
  const float* bout  = (const float*)d_in[10];
  float* out = (float*)d_out;

  char* wsb = (char*)d_ws;
  size_t off = 0;
  auto allocd = [&](size_t n)->double*{ double* p = (double*)(wsb + off); off += n*8; return p; };
  auto allocf = [&](size_t n)->float*{ float* p = (float*)(wsb + off); off += n*4; return p; };
  double* hd  = allocd(NB*NH);
  double* qd  = allocd(NB*NH);
  float*  qf  = allocf(NB*NH);
  double* gxd = allocd((size_t)NB*NH3);
  double* ghd = allocd((size_t)NB*NH3);
  double* xd  = allocd((size_t)NB*NH3);
  double* pcs = allocd((size_t)NB*8*NH);
  double* pcg = allocd((size_t)NB*2*NH);
  double* pds = allocd(NB*8);
  double* pdg = allocd(NB*2);
  float* ss  = allocf((size_t)NB*NKS);
  float* sg  = allocf((size_t)NB*NKG);
  float* tms = allocf(NB*8);
  float* tmg = allocf(NB*2);
  u64* packed_bf = (u64*)(wsb + off); off += 2*NB*8;
  u64* packed_ex = (u64*)(wsb + off); off += 2*NB*8;
  u16* apack = (u16*)(wsb + off); off += (size_t)4*48*64*8*2;  // hi+lo blocks

  size_t wpoff = (off + 255) & ~(size_t)255;
  const size_t WPBYTES = (size_t)2000*48*64*16;   // 98,304,000
  int usew = (ws_size >= wpoff + WPBYTES) ? 1 : 0;
  u16* wpack = (u16*)(wsb + wpoff);

  size_t bfoff = usew ? ((wpoff + WPBYTES + 255) & ~(size_t)255) : wpoff;
  size_t nS = (size_t)NB*NKS*NH, nG = (size_t)NB*NKG*NH;
  int usebf = (ws_size >= bfoff + (nS+nG)*2) ? 1 : 0;
  u16* sh16 = (u16*)(wsb + bfoff);
  u16* g16  = sh16 + nS;

  if (usew) k_packw<<<dim3(24000), dim3(256), 0, stream>>>(Wout, wpack);
  if (usebf) k_cast<<<dim3(4096), dim3(256), 0, stream>>>(sent, graph, sh16, g16);
  k_init<<<dim3(64), dim3(256), 0, stream>>>(enc, hd);

  for (int t=0; t<NSTEPS; t++){
    int cur = t&1;
    u64* pbf_cur = packed_bf + (size_t)cur*NB;
    u64* pex_cur = packed_ex + (size_t)cur*NB;
    k_gates<<<dim3(224), dim3(256), 0, stream>>>(hd, Wa, Wih, Whh, bih, bhh, emb,
                                                 packed_ex, qd, qf, gxd, ghd, t);
    if (usebf)
      k_scores2<1><<<dim3(320), dim3(256), 0, stream>>>(sh16, g16, sent, graph, qf, ss, sg, tms, tmg);
    else
      k_scores2<0><<<dim3(320), dim3(256), 0, stream>>>(sh16, g16, sent, graph, qf, ss, sg, tms, tmg);
    k_ct<<<dim3(320), dim3(256), 0, stream>>>(sent, graph, qd, ss, sg, tms, tmg, pcs, pcg, pds, pdg);
    k_comb<<<dim3(NB), dim3(256), 0, stream>>>(pcs, pcg, pds, pdg, gxd, ghd, hd, xd, apack, pbf_cur, pex_cur);
    float* dst = out + (size_t)t*NB*NV;
    if (usew){
      k_logv<<<dim3(500), dim3(256), 0, stream>>>(apack, wpack, bout, dst, pbf_cur);
    } else {
      k_logits<<<dim3(250), dim3(256), 0, stream>>>(xd, Wout, bout, dst, pbf_cur);
    }
    k_refine<<<dim3(NB), dim3(256), 0, stream>>>(dst, xd, Wout, bout, pbf_cur, pex_cur);
  }
}

// Round 5
// 29416.412 us; speedup vs baseline: 1.0370x; 1.0370x over previous
//
#include <hip/hip_runtime.h>
#include <hip/hip_bf16.h>
#include <math.h>

#define NB 32
#define NKS 2048
#define NKG 512
#define NH 512
#define NH3 1536
#define NV 32000
#define NSTEPS 64

typedef unsigned long long u64;
typedef unsigned int u32;
typedef unsigned short u16;
typedef __attribute__((ext_vector_type(8))) short short8;
typedef __attribute__((ext_vector_type(4))) float f32x4;

__device__ __forceinline__ float bfu(u32 u){ return __uint_as_float(u << 16); }
__device__ __forceinline__ u16 f2bf(float f){
  u32 b = __float_as_uint(f);
  return (u16)((b + 0x7FFFu + ((b>>16)&1u)) >> 16);
}

// monotone pack: larger float -> larger u64; equal float -> smaller index wins
__device__ __forceinline__ u64 packv(float v, int idx){
  u32 u = __float_as_uint(v);
  u = (u & 0x80000000u) ? ~u : (u | 0x80000000u);
  return (((u64)u) << 32) | (u32)(~(u32)idx);
}
__device__ __forceinline__ float unpackv(u64 p){
  u32 hi = (u32)(p >> 32);
  u32 u = (hi & 0x80000000u) ? (hi ^ 0x80000000u) : ~hi;
  return __uint_as_float(u);
}

// ---- one-time: pack W_out into bf16 MFMA B-fragment order (validated r4) ----
__global__ void k_packw(const float* __restrict__ W, u16* __restrict__ wp){
  long t = (long)blockIdx.x*256 + threadIdx.x;   // 6,144,000 total
  int lane = (int)(t & 63);
  long g = t >> 6;
  int kc = (int)(g % 48);
  int v16 = (int)(g / 48);
  int v = v16*16 + (lane&15);
  int k0 = kc*32 + (lane>>4)*8;
  const float4* src = (const float4*)(W + (size_t)v*NH3 + k0);
  float4 a = src[0], b = src[1];
  float vals[8] = {a.x,a.y,a.z,a.w,b.x,b.y,b.z,b.w};
  u16 o[8];
  #pragma unroll
  for (int i=0;i<8;i++) o[i] = f2bf(vals[i]);
  uint4 out;
  out.x = (u32)o[0] | ((u32)o[1]<<16);
  out.y = (u32)o[2] | ((u32)o[3]<<16);
  out.z = (u32)o[4] | ((u32)o[5]<<16);
  out.w = (u32)o[6] | ((u32)o[7]<<16);
  ((uint4*)wp)[t] = out;
}

// ---- one-time: transpose gate weights into WT[k][3584] (cols: Wa|Wih|Whh) ---
__global__ __launch_bounds__(256) void k_packt(
  const float* __restrict__ Wa, const float* __restrict__ Wih,
  const float* __restrict__ Whh, float* __restrict__ WT)
{
  int ot = blockIdx.x, kq = blockIdx.y;        // 14 x 4
  int o = ot*256 + threadIdx.x;                // 0..3583
  const float* wrow;
  if (o < 512) wrow = Wa + (size_t)o*NH;
  else if (o < 2048) wrow = Wih + (size_t)(o-512)*NH;
  else wrow = Whh + (size_t)(o-2048)*NH;
  const float4* w4 = (const float4*)wrow;
  for (int k4 = kq*32; k4 < kq*32+32; k4++){
    float4 v = w4[k4];
    WT[(size_t)(4*k4+0)*3584 + o] = v.x;
    WT[(size_t)(4*k4+1)*3584 + o] = v.y;
    WT[(size_t)(4*k4+2)*3584 + o] = v.z;
    WT[(size_t)(4*k4+3)*3584 + o] = v.w;
  }
}

__global__ void k_init(const float* __restrict__ enc, double* __restrict__ hd){
  int i = blockIdx.x*256 + threadIdx.x;   // grid 64x256 == NB*NH
  hd[i] = (double)enc[i];
}

// ---- per step (fp64, coalesced WT): q = Wa@h, gx = Wih@emb+b, gh = Whh@h+b --
// grid 56 = 14 output-tiles(256) x 4 batch-groups(8)
__global__ __launch_bounds__(256) void k_gates(
    const double* __restrict__ hd, const float* __restrict__ WT,
    const float* __restrict__ bih, const float* __restrict__ bhh,
    const float* __restrict__ emb, const u64* __restrict__ packed_ex,
    double* __restrict__ qd, double* __restrict__ gxd, double* __restrict__ ghd,
    int step)
{
  __shared__ double xs[8*512];                 // 32 KB
  int blk = blockIdx.x, tid = threadIdx.x;
  int otile = blk >> 2, bq = blk & 3, b0 = bq*8;
  int o = otile*256 + tid;                     // block-uniform matrix range
  const u64* prev = packed_ex + ((step+1)&1)*NB;
  if (otile >= 2 && otile < 8){                // Wih rows use emb[inp]
    for (int i=tid; i<8*512; i+=256){
      int bb = i>>9;
      int inp = (step==0) ? 1 : (int)(~(u32)prev[b0+bb]);
      xs[i] = (double)emb[(size_t)inp*NH + (i&511)];
    }
  } else {                                     // Wa / Whh use h
    for (int i=tid; i<8*512; i+=256) xs[i] = hd[(size_t)b0*NH + i];
  }
  __syncthreads();
  double acc[8] = {0,0,0,0,0,0,0,0};
  for (int k=0;k<512;k++){
    double w = (double)WT[(size_t)k*3584 + o];
    #pragma unroll
    for (int bb=0;bb<8;bb++) acc[bb] += w * xs[bb*512 + k];
  }
  if (o < 512){
    #pragma unroll
    for (int bb=0;bb<8;bb++) qd[(size_t)(b0+bb)*NH + o] = acc[bb];
  } else if (o < 2048){
    int oo = o-512; double bias = (double)bih[oo];
    #pragma unroll
    for (int bb=0;bb<8;bb++) gxd[(size_t)(b0+bb)*NH3 + oo] = acc[bb] + bias;
  } else {
    int oo = o-2048; double bias = (double)bhh[oo];
    #pragma unroll
    for (int bb=0;bb<8;bb++) ghd[(size_t)(b0+bb)*NH3 + oo] = acc[bb] + bias;
  }
}

// ---- per step: fused exact fp64 attention tile -------------------------------
// scores (fp64, coalesced) -> tile max -> parallel exp -> partial den + Sum w*v
// slots: b*10 + {0..7 sent, 8..9 graph}
__global__ __launch_bounds__(256) void k_att(
  const float* __restrict__ sf, const float* __restrict__ gf,
  const double* __restrict__ qd,
  double* __restrict__ pc, double* __restrict__ pden, double* __restrict__ ptm)
{
  int blk = blockIdx.x, tid = threadIdx.x;
  int b, tile, K, tslot; const float* src;
  if (blk < 256){ b = blk>>3; tile = blk&7; K = NKS; src = sf; tslot = b*10 + tile; }
  else { int bb = blk-256; b = bb>>1; tile = bb&1; K = NKG; src = gf; tslot = b*10 + 8 + tile; }
  int lane = tid&63, wv = tid>>6;
  double qv[8];
  { const double* qb = qd + (size_t)b*NH + lane*8;
    #pragma unroll
    for (int j=0;j<8;j++) qv[j] = qb[j]; }
  __shared__ double sc[256];
  __shared__ double wexp[256];
  __shared__ double red[256];
  const float* base = src + ((size_t)b*K + (size_t)tile*256)*NH;
  for (int r = wv*64; r < wv*64+64; r += 2){
    const float4* rA = (const float4*)(base + (size_t)r*NH) + lane*2;
    const float4* rB = (const float4*)(base + (size_t)(r+1)*NH) + lane*2;
    float4 a0 = rA[0], a1 = rA[1], c0f = rB[0], c1f = rB[1];
    double sA = (double)a0.x*qv[0]+(double)a0.y*qv[1]+(double)a0.z*qv[2]+(double)a0.w*qv[3]
              + (double)a1.x*qv[4]+(double)a1.y*qv[5]+(double)a1.z*qv[6]+(double)a1.w*qv[7];
    double sB = (double)c0f.x*qv[0]+(double)c0f.y*qv[1]+(double)c0f.z*qv[2]+(double)c0f.w*qv[3]
              + (double)c1f.x*qv[4]+(double)c1f.y*qv[5]+(double)c1f.z*qv[6]+(double)c1f.w*qv[7];
    #pragma unroll
    for (int off=32; off>=1; off>>=1){ sA += __shfl_xor(sA, off); sB += __shfl_xor(sB, off); }
    if (lane==0){ sc[r] = sA; sc[r+1] = sB; }
  }
  __syncthreads();
  red[tid] = sc[tid];
  __syncthreads();
  for (int s=128; s>0; s>>=1){ if (tid<s) red[tid] = fmax(red[tid], red[tid+s]); __syncthreads(); }
  double m = red[0];
  __syncthreads();
  double w = exp(sc[tid] - m);       // one fp64 exp per thread, parallel
  wexp[tid] = w;
  red[tid] = w;
  __syncthreads();
  for (int s=128; s>0; s>>=1){ if (tid<s) red[tid] += red[tid+s]; __syncthreads(); }
  if (tid==0){ pden[tslot] = red[0]; ptm[tslot] = m; }
  // weighted values: thread owns h-dims {2tid, 2tid+1}; rows are L2-hot
  double c0 = 0.0, c1 = 0.0; int h0 = tid*2;
  for (int i=0;i<256;i++){
    float2 vv = *(const float2*)(base + (size_t)i*NH + h0);
    double wi = wexp[i];
    c0 += wi*(double)vv.x; c1 += wi*(double)vv.y;
  }
  pc[(size_t)tslot*NH + h0]     = c0;
  pc[(size_t)tslot*NH + h0 + 1] = c1;
}

// ---- per step (fp64): merge tiles (exp rescale), GRU, x + split-bf16 frags ---
__global__ __launch_bounds__(256) void k_comb(
  const double* __restrict__ pc, const double* __restrict__ pden,
  const double* __restrict__ ptm,
  const double* __restrict__ gxd, const double* __restrict__ ghd,
  double* __restrict__ hd, double* __restrict__ xd, u16* __restrict__ apack,
  u64* __restrict__ pbf_cur, u64* __restrict__ pex_cur)
{
  int b = blockIdx.x, half = blockIdx.y, tid = threadIdx.x;
  int i = half*256 + tid;
  if (half==0 && tid==0){ pbf_cur[b] = 0ULL; pex_cur[b] = 0ULL; }
  __shared__ double scale[10];
  __shared__ double dent[2];
  if (tid==0){
    double ms = -1e300, mg = -1e300;
    for (int t=0;t<8;t++)  ms = fmax(ms, ptm[b*10+t]);
    for (int t=8;t<10;t++) mg = fmax(mg, ptm[b*10+t]);
    double ds = 0.0, dg = 0.0;
    for (int t=0;t<8;t++){  double s = exp(ptm[b*10+t]-ms); scale[t] = s; ds += pden[b*10+t]*s; }
    for (int t=8;t<10;t++){ double s = exp(ptm[b*10+t]-mg); scale[t] = s; dg += pden[b*10+t]*s; }
    dent[0] = ds; dent[1] = dg;
  }
  __syncthreads();
  double cs = 0.0, cg = 0.0;
  for (int t=0;t<8;t++)  cs += pc[(size_t)(b*10+t)*NH + i]*scale[t];
  for (int t=8;t<10;t++) cg += pc[(size_t)(b*10+t)*NH + i]*scale[t];
  cs /= dent[0]; cg /= dent[1];
  double xr = gxd[(size_t)b*NH3 + i],        hr = ghd[(size_t)b*NH3 + i];
  double xz = gxd[(size_t)b*NH3 + NH + i],   hz = ghd[(size_t)b*NH3 + NH + i];
  double xn = gxd[(size_t)b*NH3 + 2*NH + i], hn = ghd[(size_t)b*NH3 + 2*NH + i];
  double r = 1.0/(1.0+exp(-(xr+hr)));
  double z = 1.0/(1.0+exp(-(xz+hz)));
  double nn = tanh(xn + r*hn);
  double hold = hd[(size_t)b*NH + i];
  double hnew = (1.0 - z)*nn + z*hold;
  hd[(size_t)b*NH + i] = hnew;
  int mt = b>>4, row = b&15;
  double vals[3] = {hnew, cg, cs};
  #pragma unroll
  for (int c=0;c<3;c++){
    int col = c*NH + i;
    xd[(size_t)b*NH3 + col] = vals[c];
    int kc = col>>5, kg = (col&31)>>3, j = col&7;
    int lane = row + 16*kg;
    size_t base = ((size_t)(mt*48+kc)*64 + lane)*8 + j;
    float xf = (float)vals[c];
    u16 hi = f2bf(xf);
    float rem = (float)(vals[c] - (double)bfu((u32)hi));
    apack[base] = hi;
    apack[base + (size_t)2*48*64*8] = f2bf(rem);   // lo block after hi block
  }
}

// --------- per step: logits via split-bf16 MFMA (validated r4) ---------------
__global__ __launch_bounds__(256) void k_logv(
  const u16* __restrict__ apack, const u16* __restrict__ wpack,
  const float* __restrict__ bout, float* __restrict__ dst,
  u64* __restrict__ pbf_cur)
{
  int tid = threadIdx.x;
  int wv = tid>>6, lane = tid&63;
  int v16 = blockIdx.x*4 + wv;                    // 500 blocks -> 2000 tiles
  const short8* bp = (const short8*)wpack + (size_t)v16*48*64 + lane;
  const short8* ap = (const short8*)apack + lane;
  f32x4 acc0 = {0.f,0.f,0.f,0.f}, acc1 = {0.f,0.f,0.f,0.f};
  #pragma unroll 4
  for (int kc=0; kc<48; kc++){
    short8 bf = bp[(size_t)kc*64];
    short8 a0h = ap[(size_t)kc*64];
    short8 a1h = ap[(size_t)(48+kc)*64];
    short8 a0l = ap[(size_t)(96+kc)*64];
    short8 a1l = ap[(size_t)(144+kc)*64];
    acc0 = __builtin_amdgcn_mfma_f32_16x16x32_bf16(a0h, bf, acc0, 0, 0, 0);
    acc0 = __builtin_amdgcn_mfma_f32_16x16x32_bf16(a0l, bf, acc0, 0, 0, 0);
    acc1 = __builtin_amdgcn_mfma_f32_16x16x32_bf16(a1h, bf, acc1, 0, 0, 0);
    acc1 = __builtin_amdgcn_mfma_f32_16x16x32_bf16(a1l, bf, acc1, 0, 0, 0);
  }
  __shared__ u64 smax[NB];
  if (tid < NB) smax[tid] = 0ULL;
  __syncthreads();
  int col = v16*16 + (lane&15);
  float bias = bout[col];
  int r0 = (lane>>4)*4;
  #pragma unroll
  for (int r=0;r<4;r++){
    int b0 = r0 + r;
    float v0 = acc0[r] + bias;
    dst[(size_t)b0*NV + col] = v0;
    atomicMax(&smax[b0], packv(v0, col));
    int b1 = 16 + b0;
    float v1 = acc1[r] + bias;
    dst[(size_t)b1*NV + col] = v1;
    atomicMax(&smax[b1], packv(v1, col));
  }
  __syncthreads();
  if (tid < NB) atomicMax(&pbf_cur[tid], smax[tid]);
}

// ---- per step: fp64 argmax among near-max candidates (validated r4) ---------
__global__ __launch_bounds__(256) void k_refine(
  float* __restrict__ logits, const double* __restrict__ xd,
  const float* __restrict__ Wout, const float* __restrict__ bout,
  const u64* __restrict__ pbf_cur, u64* __restrict__ pex_cur)
{
  int b = blockIdx.x, tid = threadIdx.x;
  __shared__ double xs[NH3];          // 12 KB
  for (int i=tid;i<NH3;i+=256) xs[i] = xd[(size_t)b*NH3 + i];
  float maxv = unpackv(pbf_cur[b]);
  __shared__ int cnt;
  __shared__ int cand[2048];          // 8 KB
  __shared__ double cval[2048];       // 16 KB
  const float4* lg = (const float4*)(logits + (size_t)b*NV);
  float margin = 1.0f;
  for (int attempt=0; attempt<2; attempt++){
    if (tid==0) cnt = 0;
    __syncthreads();
    float thr = maxv - margin;
    for (int i=tid; i<NV/4; i+=256){
      float4 v = lg[i];
      if (v.x>thr){ int p=atomicAdd(&cnt,1); if(p<2048) cand[p]=i*4+0; }
      if (v.y>thr){ int p=atomicAdd(&cnt,1); if(p<2048) cand[p]=i*4+1; }
      if (v.z>thr){ int p=atomicAdd(&cnt,1); if(p<2048) cand[p]=i*4+2; }
      if (v.w>thr){ int p=atomicAdd(&cnt,1); if(p<2048) cand[p]=i*4+3; }
    }
    __syncthreads();
    if (cnt <= 2048) break;
    margin = 0.125f;                  // bulk err << 0.125, true argmax still included
    __syncthreads();
  }
  int n = min(cnt, 2048);
  int wv = tid>>6, lane = tid&63;
  for (int c=wv; c<n; c+=4){
    int v = cand[c];
    const float4* wr = (const float4*)(Wout + (size_t)v*NH3);
    double a = 0.0;
    #pragma unroll
    for (int i=0;i<6;i++){
      int e = lane + 64*i;
      float4 w4 = wr[e];
      a += (double)w4.x*xs[e*4+0] + (double)w4.y*xs[e*4+1]
         + (double)w4.z*xs[e*4+2] + (double)w4.w*xs[e*4+3];
    }
    #pragma unroll
    for (int off=32; off>=1; off>>=1) a += __shfl_xor(a, off);
    if (lane==0){
      double av = a + (double)bout[v];
      cval[c] = av;
      logits[(size_t)b*NV + v] = (float)av;
    }
  }
  __syncthreads();
  if (tid==0){
    double bv = -1e300; int bi = 0x7fffffff;
    for (int c=0;c<n;c++){
      if (cval[c] > bv || (cval[c] == bv && cand[c] < bi)){ bv = cval[c]; bi = cand[c]; }
    }
    pex_cur[b] = packv((float)bv, bi);
  }
}

// -------- fp32 fallback bulk logits (used only if ws can't hold packed W) ----
__global__ __launch_bounds__(256) void k_logits(
  const double* __restrict__ xd, const float* __restrict__ Wout,
  const float* __restrict__ bout, float* __restrict__ dst,
  u64* __restrict__ pbf_cur)
{
  __shared__ float4 xs4[NB*128];
  int tid = threadIdx.x;
  int bg = tid>>6, lane = tid&63;
  int vbase = blockIdx.x*128;
  int v0 = vbase + lane, v1 = vbase + 64 + lane;
  float acc0[8] = {0.f,0.f,0.f,0.f,0.f,0.f,0.f,0.f};
  float acc1[8] = {0.f,0.f,0.f,0.f,0.f,0.f,0.f,0.f};
  for (int c=0;c<3;c++){
    int kb = c*NH;
    for (int i=tid;i<NB*128;i+=256){
      int b=i>>7, kk=i&127;
      float4 t;
      t.x = (float)xd[(size_t)b*NH3 + kb + kk*4+0];
      t.y = (float)xd[(size_t)b*NH3 + kb + kk*4+1];
      t.z = (float)xd[(size_t)b*NH3 + kb + kk*4+2];
      t.w = (float)xd[(size_t)b*NH3 + kb + kk*4+3];
      xs4[i] = t;
    }
    __syncthreads();
    const float4* w0 = (const float4*)(Wout + (size_t)v0*NH3 + kb);
    const float4* w1 = (const float4*)(Wout + (size_t)v1*NH3 + kb);
    for (int k4=0;k4<128;k4++){
      float4 a = w0[k4], bb = w1[k4];
      #pragma unroll
      for (int j=0;j<8;j++){
        float4 xv = xs4[(bg*8+j)*128 + k4];
        acc0[j] += a.x*xv.x;  acc0[j] += a.y*xv.y;  acc0[j] += a.z*xv.z;  acc0[j] += a.w*xv.w;
        acc1[j] += bb.x*xv.x; acc1[j] += bb.y*xv.y; acc1[j] += bb.z*xv.z; acc1[j] += bb.w*xv.w;
      }
    }
    __syncthreads();
  }
  u64* smax = (u64*)xs4;
  if (tid<NB) smax[tid] = 0ULL;
  __syncthreads();
  float b0 = bout[v0], b1 = bout[v1];
  #pragma unroll
  for (int j=0;j<8;j++){
    int b = bg*8+j;
    float r0 = acc0[j]+b0, r1 = acc1[j]+b1;
    dst[(size_t)b*NV + v0] = r0;
    dst[(size_t)b*NV + v1] = r1;
    u64 p0 = packv(r0, v0), p1 = packv(r1, v1);
    atomicMax(&smax[b], p0>p1?p0:p1);
  }
  __syncthreads();
  if (tid<NB) atomicMax(&pbf_cur[tid], smax[tid]);
}

extern "C" void kernel_launch(void* const* d_in, const int* in_sizes, int n_in,
                              void* d_out, int out_size, void* d_ws, size_t ws_size,
                              hipStream_t stream) {
  const float* sent  = (const float*)d_in[0];
  const float* graph = (const float*)d_in[1];
  const float* enc   = (const float*)d_in[2];
  const float* Wa    = (const float*)d_in[3];
  const float* emb   = (const float*)d_in[4];
  const float* Wih   = (const float*)d_in[5];
  const float* Whh   = (const float*)d_in[6];
  const float* bih   = (const float*)d_in[7];
  const float* bhh   = (const float*)d_in[8];
  const float* Wout  = (const float*)d_in[9];
  const float* bout  = (const float*)d_in[10];
  float* out = (float*)d_out;

  char* wsb = (char*)d_ws;
  size_t off = 0;
  auto allocd = [&](size_t n)->double*{ double* p = (double*)(wsb + off); off += n*8; return p; };
  auto allocf = [&](size_t n)->float*{ float* p = (float*)(wsb + off); off += n*4; return p; };
  double* hd  = allocd(NB*NH);
  double* qd  = allocd(NB*NH);
  double* gxd = allocd((size_t)NB*NH3);
  double* ghd = allocd((size_t)NB*NH3);
  double* xd  = allocd((size_t)NB*NH3);
  double* pc  = allocd((size_t)NB*10*NH);
  double* pden= allocd(NB*10);
  double* ptm = allocd(NB*10);
  u64* packed_bf = (u64*)(wsb + off); off += 2*NB*8;
  u64* packed_ex = (u64*)(wsb + off); off += 2*NB*8;
  u16* apack = (u16*)(wsb + off); off += (size_t)4*48*64*8*2;  // hi+lo blocks
  float* WT = allocf((size_t)512*3584);                        // 7.34 MB

  size_t wpoff = (off + 255) & ~(size_t)255;
  const size_t WPBYTES = (size_t)2000*48*64*16;   // 98,304,000
  int usew = (ws_size >= wpoff + WPBYTES) ? 1 : 0;
  u16* wpack = (u16*)(wsb + wpoff);

  k_packt<<<dim3(14,4), dim3(256), 0, stream>>>(Wa, Wih, Whh, WT);
  if (usew) k_packw<<<dim3(24000), dim3(256), 0, stream>>>(Wout, wpack);
  k_init<<<dim3(64), dim3(256), 0, stream>>>(enc, hd);

  for (int t=0; t<NSTEPS; t++){
    int cur = t&1;
    u64* pbf_cur = packed_bf + (size_t)cur*NB;
    u64* pex_cur = packed_ex + (size_t)cur*NB;
    k_gates<<<dim3(56), dim3(256), 0, stream>>>(hd, WT, bih, bhh, emb, packed_ex,
                                                qd, gxd, ghd, t);
    k_att<<<dim3(320), dim3(256), 0, stream>>>(sent, graph, qd, pc, pden, ptm);
    k_comb<<<dim3(32,2), dim3(256), 0, stream>>>(pc, pden, ptm, gxd, ghd, hd, xd,
                                                 apack, pbf_cur, pex_cur);
    float* dst = out + (size_t)t*NB*NV;
    if (usew){
      k_logv<<<dim3(500), dim3(256), 0, stream>>>(apack, wpack, bout, dst, pbf_cur);
    } else {
      k_logits<<<dim3(250), dim3(256), 0, stream>>>(xd, Wout, bout, dst, pbf_cur);
    }
    k_refine<<<dim3(32), dim3(256), 0, stream>>>(dst, xd, Wout, bout, pbf_cur, pex_cur);
  }
}

// Round 6
// 26040.265 us; speedup vs baseline: 1.1715x; 1.1297x over previous
//
#include <hip/hip_runtime.h>
#include <hip/hip_bf16.h>
#include <math.h>

#define NB 32
#define NKS 2048
#define NKG 512
#define NH 512
#define NH3 1536
#define NV 32000
#define NSTEPS 64

typedef unsigned long long u64;
typedef unsigned int u32;
typedef unsigned short u16;
typedef __attribute__((ext_vector_type(8))) short short8;
typedef __attribute__((ext_vector_type(4))) float f32x4;

__device__ __forceinline__ float bfu(u32 u){ return __uint_as_float(u << 16); }
__device__ __forceinline__ u16 f2bf(float f){
  u32 b = __float_as_uint(f);
  return (u16)((b + 0x7FFFu + ((b>>16)&1u)) >> 16);
}

// monotone pack: larger float -> larger u64; equal float -> smaller index wins
__device__ __forceinline__ u64 packv(float v, int idx){
  u32 u = __float_as_uint(v);
  u = (u & 0x80000000u) ? ~u : (u | 0x80000000u);
  return (((u64)u) << 32) | (u32)(~(u32)idx);
}
__device__ __forceinline__ float unpackv(u64 p){
  u32 hi = (u32)(p >> 32);
  u32 u = (hi & 0x80000000u) ? (hi ^ 0x80000000u) : ~hi;
  return __uint_as_float(u);
}

// ---- one-time: pack W_out into bf16 MFMA B-fragment order (validated r4) ----
__global__ void k_packw(const float* __restrict__ W, u16* __restrict__ wp){
  long t = (long)blockIdx.x*256 + threadIdx.x;   // 6,144,000 total
  int lane = (int)(t & 63);
  long g = t >> 6;
  int kc = (int)(g % 48);
  int v16 = (int)(g / 48);
  int v = v16*16 + (lane&15);
  int k0 = kc*32 + (lane>>4)*8;
  const float4* src = (const float4*)(W + (size_t)v*NH3 + k0);
  float4 a = src[0], b = src[1];
  float vals[8] = {a.x,a.y,a.z,a.w,b.x,b.y,b.z,b.w};
  u16 o[8];
  #pragma unroll
  for (int i=0;i<8;i++) o[i] = f2bf(vals[i]);
  uint4 out;
  out.x = (u32)o[0] | ((u32)o[1]<<16);
  out.y = (u32)o[2] | ((u32)o[3]<<16);
  out.z = (u32)o[4] | ((u32)o[5]<<16);
  out.w = (u32)o[6] | ((u32)o[7]<<16);
  ((uint4*)wp)[t] = out;
}

// ---- once per launch: hdT[k][b] = enc, embT[k][b] = emb[BOS] ---------------
__global__ void k_init(const float* __restrict__ enc, const float* __restrict__ emb,
                       double* __restrict__ hdT, double* __restrict__ embT){
  int i = blockIdx.x*256 + threadIdx.x;   // 64x256 = 16384 = NB*NH
  int b = i>>9, k = i&511;
  hdT[k*NB + b]  = (double)enc[i];
  embT[k*NB + b] = (double)emb[NH + k];   // BOS token = 1
}

// ---- per step (fp64): q = Wa@h, gx = Wih@emb+b, gh = Whh@h+b ---------------
// grid 448: blk<64 -> Wa rows; blk<256 -> Wih; else Whh. 8 rows x 32 b per blk.
__global__ __launch_bounds__(256) void k_gates(
    const double* __restrict__ hdT, const double* __restrict__ embT,
    const float* __restrict__ Wa, const float* __restrict__ Wih,
    const float* __restrict__ Whh,
    const float* __restrict__ bih, const float* __restrict__ bhh,
    double* __restrict__ qd, double* __restrict__ gxd, double* __restrict__ ghd)
{
  __shared__ float Wlds[8*512];            // 16 KB
  __shared__ double xls[64*NB];            // 16 KB per k-chunk
  int blk = blockIdx.x, tid = threadIdx.x;
  const float* Wseg; const double* xg; int row0;
  if (blk < 64){ Wseg = Wa; row0 = blk*8; xg = hdT; }
  else if (blk < 256){ Wseg = Wih; row0 = (blk-64)*8; xg = embT; }
  else { Wseg = Whh; row0 = (blk-256)*8; xg = hdT; }
  { const float4* src = (const float4*)(Wseg + (size_t)row0*NH);
    float4* d4 = (float4*)Wlds;
    for (int j=tid; j<1024; j+=256) d4[j] = src[j]; }
  int ol = tid>>5, b = tid&31;
  double acc = 0.0;
  for (int kc=0; kc<8; kc++){
    __syncthreads();
    for (int j=tid; j<64*NB; j+=256) xls[j] = xg[(size_t)kc*64*NB + j];
    __syncthreads();
    #pragma unroll 16
    for (int kk=0; kk<64; kk++)
      acc += (double)Wlds[ol*512 + kc*64 + kk] * xls[kk*NB + b];
  }
  if (blk < 64){
    qd[(size_t)b*NH + row0 + ol] = acc;
  } else if (blk < 256){
    int o = row0 + ol;
    gxd[(size_t)b*NH3 + o] = acc + (double)bih[o];
  } else {
    int o = row0 + ol;
    ghd[(size_t)b*NH3 + o] = acc + (double)bhh[o];
  }
}

// ---- per step: fused exact fp64 attention, 128-key tiles --------------------
// grid 640: blk<512 sent (16 tiles/b), else graph (4 tiles/b). slots b*20+{0..19}
__global__ __launch_bounds__(256) void k_att(
  const float* __restrict__ sf, const float* __restrict__ gf,
  const double* __restrict__ qd,
  double* __restrict__ pc, double* __restrict__ pden, double* __restrict__ ptm)
{
  int blk = blockIdx.x, tid = threadIdx.x;
  int b, tile, K, tslot; const float* src;
  if (blk < 512){ b = blk>>4; tile = blk&15; K = NKS; src = sf; tslot = b*20 + tile; }
  else { int bb = blk-512; b = bb>>2; tile = bb&3; K = NKG; src = gf; tslot = b*20 + 16 + tile; }
  int lane = tid&63, wv = tid>>6;
  double qv[8];
  { const double* qb = qd + (size_t)b*NH + lane*8;
    #pragma unroll
    for (int j=0;j<8;j++) qv[j] = qb[j]; }
  __shared__ double sc[128];
  __shared__ double wexp[128];
  __shared__ double red[256];
  const float* base = src + ((size_t)b*K + (size_t)tile*128)*NH;
  for (int r = wv*32; r < wv*32+32; r += 2){
    const float4* rA = (const float4*)(base + (size_t)r*NH) + lane*2;
    const float4* rB = (const float4*)(base + (size_t)(r+1)*NH) + lane*2;
    float4 a0 = rA[0], a1 = rA[1], c0f = rB[0], c1f = rB[1];
    double sA = (double)a0.x*qv[0]+(double)a0.y*qv[1]+(double)a0.z*qv[2]+(double)a0.w*qv[3]
              + (double)a1.x*qv[4]+(double)a1.y*qv[5]+(double)a1.z*qv[6]+(double)a1.w*qv[7];
    double sB = (double)c0f.x*qv[0]+(double)c0f.y*qv[1]+(double)c0f.z*qv[2]+(double)c0f.w*qv[3]
              + (double)c1f.x*qv[4]+(double)c1f.y*qv[5]+(double)c1f.z*qv[6]+(double)c1f.w*qv[7];
    #pragma unroll
    for (int off=32; off>=1; off>>=1){ sA += __shfl_xor(sA, off); sB += __shfl_xor(sB, off); }
    if (lane==0){ sc[r] = sA; sc[r+1] = sB; }
  }
  __syncthreads();
  red[tid] = (tid < 128) ? sc[tid] : -1.0e300;
  __syncthreads();
  for (int s=128; s>0; s>>=1){ if (tid<s) red[tid] = fmax(red[tid], red[tid+s]); __syncthreads(); }
  double m = red[0];
  __syncthreads();
  double w = 0.0;
  if (tid < 128){ w = exp(sc[tid] - m); wexp[tid] = w; }
  red[tid] = w;
  __syncthreads();
  for (int s=128; s>0; s>>=1){ if (tid<s) red[tid] += red[tid+s]; __syncthreads(); }
  if (tid==0){ pden[tslot] = red[0]; ptm[tslot] = m; }
  // weighted values: thread owns dims {2tid,2tid+1}; rows L2-hot from score pass
  double c0a=0.0, c0b=0.0, c1a=0.0, c1b=0.0; int h0 = tid*2;
  for (int i=0;i<128;i+=2){
    float2 v0 = *(const float2*)(base + (size_t)i*NH + h0);
    float2 v1 = *(const float2*)(base + (size_t)(i+1)*NH + h0);
    double w0 = wexp[i], w1 = wexp[i+1];
    c0a += w0*(double)v0.x; c1a += w0*(double)v0.y;
    c0b += w1*(double)v1.x; c1b += w1*(double)v1.y;
  }
  pc[(size_t)tslot*NH + h0]     = c0a + c0b;
  pc[(size_t)tslot*NH + h0 + 1] = c1a + c1b;
}

// ---- per step (fp64): merge 20 tiles, GRU, x + hdT + split-bf16 frags -------
__global__ __launch_bounds__(256) void k_comb(
  const double* __restrict__ pc, const double* __restrict__ pden,
  const double* __restrict__ ptm,
  const double* __restrict__ gxd, const double* __restrict__ ghd,
  double* __restrict__ hdT, double* __restrict__ xd, u16* __restrict__ apack,
  u64* __restrict__ pbf)
{
  int b = blockIdx.x, half = blockIdx.y, tid = threadIdx.x;
  int i = half*256 + tid;
  if (half==0 && tid==0) pbf[b] = 0ULL;
  __shared__ double scale[20];
  __shared__ double dent[2];
  if (tid==0){
    double ms = -1e300, mg = -1e300;
    for (int t=0;t<16;t++)  ms = fmax(ms, ptm[b*20+t]);
    for (int t=16;t<20;t++) mg = fmax(mg, ptm[b*20+t]);
    double ds = 0.0, dg = 0.0;
    for (int t=0;t<16;t++){  double s = exp(ptm[b*20+t]-ms); scale[t] = s; ds += pden[b*20+t]*s; }
    for (int t=16;t<20;t++){ double s = exp(ptm[b*20+t]-mg); scale[t] = s; dg += pden[b*20+t]*s; }
    dent[0] = ds; dent[1] = dg;
  }
  __syncthreads();
  double cs = 0.0, cg = 0.0;
  for (int t=0;t<16;t++)  cs += pc[(size_t)(b*20+t)*NH + i]*scale[t];
  for (int t=16;t<20;t++) cg += pc[(size_t)(b*20+t)*NH + i]*scale[t];
  cs /= dent[0]; cg /= dent[1];
  double xr = gxd[(size_t)b*NH3 + i],        hr = ghd[(size_t)b*NH3 + i];
  double xz = gxd[(size_t)b*NH3 + NH + i],   hz = ghd[(size_t)b*NH3 + NH + i];
  double xn = gxd[(size_t)b*NH3 + 2*NH + i], hn = ghd[(size_t)b*NH3 + 2*NH + i];
  double r = 1.0/(1.0+exp(-(xr+hr)));
  double z = 1.0/(1.0+exp(-(xz+hz)));
  double nn = tanh(xn + r*hn);
  double hold = hdT[(size_t)i*NB + b];
  double hnew = (1.0 - z)*nn + z*hold;
  hdT[(size_t)i*NB + b] = hnew;
  int mt = b>>4, row = b&15;
  double vals[3] = {hnew, cg, cs};
  #pragma unroll
  for (int c=0;c<3;c++){
    int col = c*NH + i;
    xd[(size_t)b*NH3 + col] = vals[c];
    int kc = col>>5, kg = (col&31)>>3, j = col&7;
    int lane = row + 16*kg;
    size_t base = ((size_t)(mt*48+kc)*64 + lane)*8 + j;
    float xf = (float)vals[c];
    u16 hi = f2bf(xf);
    float rem = (float)(vals[c] - (double)bfu((u32)hi));
    apack[base] = hi;
    apack[base + (size_t)2*48*64*8] = f2bf(rem);   // lo block after hi block
  }
}

// --------- per step: logits via split-bf16 MFMA (validated r4) ---------------
__global__ __launch_bounds__(256) void k_logv(
  const u16* __restrict__ apack, const u16* __restrict__ wpack,
  const float* __restrict__ bout, float* __restrict__ dst,
  u64* __restrict__ pbf)
{
  int tid = threadIdx.x;
  int wv = tid>>6, lane = tid&63;
  int v16 = blockIdx.x*4 + wv;                    // 500 blocks -> 2000 tiles
  const short8* bp = (const short8*)wpack + (size_t)v16*48*64 + lane;
  const short8* ap = (const short8*)apack + lane;
  f32x4 acc0 = {0.f,0.f,0.f,0.f}, acc1 = {0.f,0.f,0.f,0.f};
  #pragma unroll 4
  for (int kc=0; kc<48; kc++){
    short8 bf = bp[(size_t)kc*64];
    short8 a0h = ap[(size_t)kc*64];
    short8 a1h = ap[(size_t)(48+kc)*64];
    short8 a0l = ap[(size_t)(96+kc)*64];
    short8 a1l = ap[(size_t)(144+kc)*64];
    acc0 = __builtin_amdgcn_mfma_f32_16x16x32_bf16(a0h, bf, acc0, 0, 0, 0);
    acc0 = __builtin_amdgcn_mfma_f32_16x16x32_bf16(a0l, bf, acc0, 0, 0, 0);
    acc1 = __builtin_amdgcn_mfma_f32_16x16x32_bf16(a1h, bf, acc1, 0, 0, 0);
    acc1 = __builtin_amdgcn_mfma_f32_16x16x32_bf16(a1l, bf, acc1, 0, 0, 0);
  }
  __shared__ u64 smax[NB];
  if (tid < NB) smax[tid] = 0ULL;
  __syncthreads();
  int col = v16*16 + (lane&15);
  float bias = bout[col];
  int r0 = (lane>>4)*4;
  #pragma unroll
  for (int r=0;r<4;r++){
    int b0 = r0 + r;
    float v0 = acc0[r] + bias;
    dst[(size_t)b0*NV + col] = v0;
    atomicMax(&smax[b0], packv(v0, col));
    int b1 = 16 + b0;
    float v1 = acc1[r] + bias;
    dst[(size_t)b1*NV + col] = v1;
    atomicMax(&smax[b1], packv(v1, col));
  }
  __syncthreads();
  if (tid < NB) atomicMax(&pbf[tid], smax[tid]);
}

// ---- per step: fp64 argmax among near-max candidates; writes embT for t+1 ---
__global__ __launch_bounds__(256) void k_refine(
  float* __restrict__ logits, const double* __restrict__ xd,
  const float* __restrict__ Wout, const float* __restrict__ bout,
  const float* __restrict__ emb, const u64* __restrict__ pbf,
  double* __restrict__ embT)
{
  int b = blockIdx.x, tid = threadIdx.x;
  __shared__ double xs[NH3];          // 12 KB
  for (int i=tid;i<NH3;i+=256) xs[i] = xd[(size_t)b*NH3 + i];
  float maxv = unpackv(pbf[b]);
  __shared__ int cnt;
  __shared__ int cand[2048];          // 8 KB
  __shared__ double cval[2048];       // 16 KB
  const float4* lg = (const float4*)(logits + (size_t)b*NV);
  float margin = 1.0f;
  for (int attempt=0; attempt<2; attempt++){
    if (tid==0) cnt = 0;
    __syncthreads();
    float thr = maxv - margin;
    for (int i=tid; i<NV/4; i+=256){
      float4 v = lg[i];
      if (v.x>thr){ int p=atomicAdd(&cnt,1); if(p<2048) cand[p]=i*4+0; }
      if (v.y>thr){ int p=atomicAdd(&cnt,1); if(p<2048) cand[p]=i*4+1; }
      if (v.z>thr){ int p=atomicAdd(&cnt,1); if(p<2048) cand[p]=i*4+2; }
      if (v.w>thr){ int p=atomicAdd(&cnt,1); if(p<2048) cand[p]=i*4+3; }
    }
    __syncthreads();
    if (cnt <= 2048) break;
    margin = 0.125f;                  // bulk err << 0.125, true argmax still included
    __syncthreads();
  }
  int n = min(cnt, 2048);
  int wv = tid>>6, lane = tid&63;
  for (int c=wv; c<n; c+=4){
    int v = cand[c];
    const float4* wr = (const float4*)(Wout + (size_t)v*NH3);
    double a = 0.0;
    #pragma unroll
    for (int i=0;i<6;i++){
      int e = lane + 64*i;
      float4 w4 = wr[e];
      a += (double)w4.x*xs[e*4+0] + (double)w4.y*xs[e*4+1]
         + (double)w4.z*xs[e*4+2] + (double)w4.w*xs[e*4+3];
    }
    #pragma unroll
    for (int off=32; off>=1; off>>=1) a += __shfl_xor(a, off);
    if (lane==0){
      double av = a + (double)bout[v];
      cval[c] = av;
      logits[(size_t)b*NV + v] = (float)av;
    }
  }
  __syncthreads();
  __shared__ int bidx;
  if (tid==0){
    double bv = -1e300; int bi = 0x7fffffff;
    for (int c=0;c<n;c++){
      if (cval[c] > bv || (cval[c] == bv && cand[c] < bi)){ bv = cval[c]; bi = cand[c]; }
    }
    bidx = bi;
  }
  __syncthreads();
  int bi = bidx;
  for (int k=tid; k<NH; k+=256)
    embT[(size_t)k*NB + b] = (double)emb[(size_t)bi*NH + k];
}

// -------- fp32 fallback bulk logits (used only if ws can't hold packed W) ----
__global__ __launch_bounds__(256) void k_logits(
  const double* __restrict__ xd, const float* __restrict__ Wout,
  const float* __restrict__ bout, float* __restrict__ dst,
  u64* __restrict__ pbf)
{
  __shared__ float4 xs4[NB*128];
  int tid = threadIdx.x;
  int bg = tid>>6, lane = tid&63;
  int vbase = blockIdx.x*128;
  int v0 = vbase + lane, v1 = vbase + 64 + lane;
  float acc0[8] = {0.f,0.f,0.f,0.f,0.f,0.f,0.f,0.f};
  float acc1[8] = {0.f,0.f,0.f,0.f,0.f,0.f,0.f,0.f};
  for (int c=0;c<3;c++){
    int kb = c*NH;
    for (int i=tid;i<NB*128;i+=256){
      int b=i>>7, kk=i&127;
      float4 t;
      t.x = (float)xd[(size_t)b*NH3 + kb + kk*4+0];
      t.y = (float)xd[(size_t)b*NH3 + kb + kk*4+1];
      t.z = (float)xd[(size_t)b*NH3 + kb + kk*4+2];
      t.w = (float)xd[(size_t)b*NH3 + kb + kk*4+3];
      xs4[i] = t;
    }
    __syncthreads();
    const float4* w0 = (const float4*)(Wout + (size_t)v0*NH3 + kb);
    const float4* w1 = (const float4*)(Wout + (size_t)v1*NH3 + kb);
    for (int k4=0;k4<128;k4++){
      float4 a = w0[k4], bb = w1[k4];
      #pragma unroll
      for (int j=0;j<8;j++){
        float4 xv = xs4[(bg*8+j)*128 + k4];
        acc0[j] += a.x*xv.x;  acc0[j] += a.y*xv.y;  acc0[j] += a.z*xv.z;  acc0[j] += a.w*xv.w;
        acc1[j] += bb.x*xv.x; acc1[j] += bb.y*xv.y; acc1[j] += bb.z*xv.z; acc1[j] += bb.w*xv.w;
      }
    }
    __syncthreads();
  }
  u64* smax = (u64*)xs4;
  if (tid<NB) smax[tid] = 0ULL;
  __syncthreads();
  float b0 = bout[v0], b1 = bout[v1];
  #pragma unroll
  for (int j=0;j<8;j++){
    int b = bg*8+j;
    float r0 = acc0[j]+b0, r1 = acc1[j]+b1;
    dst[(size_t)b*NV + v0] = r0;
    dst[(size_t)b*NV + v1] = r1;
    u64 p0 = packv(r0, v0), p1 = packv(r1, v1);
    atomicMax(&smax[b], p0>p1?p0:p1);
  }
  __syncthreads();
  if (tid<NB) atomicMax(&pbf[tid], smax[tid]);
}

extern "C" void kernel_launch(void* const* d_in, const int* in_sizes, int n_in,
                              void* d_out, int out_size, void* d_ws, size_t ws_size,
                              hipStream_t stream) {
  const float* sent  = (const float*)d_in[0];
  const float* graph = (const float*)d_in[1];
  const float* enc   = (const float*)d_in[2];
  const float* Wa    = (const float*)d_in[3];
  const float* emb   = (const float*)d_in[4];
  const float* Wih   = (const float*)d_in[5];
  const float* Whh   = (const float*)d_in[6];
  const float* bih   = (const float*)d_in[7];
  const float* bhh   = (const float*)d_in[8];
  const float* Wout  = (const float*)d_in[9];
  const float* bout  = (const float*)d_in[10];
  float* out = (float*)d_out;

  char* wsb = (char*)d_ws;
  size_t off = 0;
  auto allocd = [&](size_t n)->double*{ double* p = (double*)(wsb + off); off += n*8; return p; };
  double* hdT = allocd(NB*NH);
  double* embT= allocd(NB*NH);
  double* qd  = allocd(NB*NH);
  double* gxd = allocd((size_t)NB*NH3);
  double* ghd = allocd((size_t)NB*NH3);
  double* xd  = allocd((size_t)NB*NH3);
  double* pc  = allocd((size_t)NB*20*NH);
  double* pden= allocd(NB*20);
  double* ptm = allocd(NB*20);
  u64* pbf = (u64*)(wsb + off); off += NB*8;
  u16* apack = (u16*)(wsb + off); off += (size_t)4*48*64*8*2;  // hi+lo blocks

  size_t wpoff = (off + 255) & ~(size_t)255;
  const size_t WPBYTES = (size_t)2000*48*64*16;   // 98,304,000
  int usew = (ws_size >= wpoff + WPBYTES) ? 1 : 0;
  u16* wpack = (u16*)(wsb + wpoff);

  if (usew) k_packw<<<dim3(24000), dim3(256), 0, stream>>>(Wout, wpack);
  k_init<<<dim3(64), dim3(256), 0, stream>>>(enc, emb, hdT, embT);

  for (int t=0; t<NSTEPS; t++){
    k_gates<<<dim3(448), dim3(256), 0, stream>>>(hdT, embT, Wa, Wih, Whh, bih, bhh,
                                                 qd, gxd, ghd);
    k_att<<<dim3(640), dim3(256), 0, stream>>>(sent, graph, qd, pc, pden, ptm);
    k_comb<<<dim3(32,2), dim3(256), 0, stream>>>(pc, pden, ptm, gxd, ghd, hdT, xd,
                                                 apack, pbf);
    float* dst = out + (size_t)t*NB*NV;
    if (usew){
      k_logv<<<dim3(500), dim3(256), 0, stream>>>(apack, wpack, bout, dst, pbf);
    } else {
      k_logits<<<dim3(250), dim3(256), 0, stream>>>(xd, Wout, bout, dst, pbf);
    }
    k_refine<<<dim3(32), dim3(256), 0, stream>>>(dst, xd, Wout, bout, emb, pbf, embT);
  }
}